// Round 14
// baseline (139.357 us; speedup 1.0000x reference)
//
#include <hip/hip_runtime.h>
#include <hip/hip_bf16.h>

// Problem constants
#define B_  8
#define TQ_ 128
#define TK_ 512
#define D_  256
#define H_  256

#define KSCALE 2.8853900817779268f   // 2*log2(e): exp(2x) = exp2(KSCALE*x)

__device__ __forceinline__ float fast_exp2(float x) {
    return __builtin_amdgcn_exp2f(x);   // v_exp_f32: 2^x
}
__device__ __forceinline__ float fast_rcp(float y) {
    return __builtin_amdgcn_rcpf(y);
}

__device__ __forceinline__ float wave_red_min(float v) {
#pragma unroll
    for (int o = 32; o > 0; o >>= 1) v = fminf(v, __shfl_xor(v, o));
    return v;
}
__device__ __forceinline__ float wave_red_sum(float v) {
#pragma unroll
    for (int o = 32; o > 0; o >>= 1) v += __shfl_xor(v, o);
    return v;
}

// ---------------------------------------------------------------------------
// Kernel 1: projections, outputs pre-scaled by KSCALE. 16-row tiles.
//   blocks [0,64):   qp[b][q][h]  = KSCALE * queries·Wq  (row-major)
//   blocks [64,320): kpT[b][h][k] = KSCALE * keys·Wk     (transposed; tile
//                    skipped when r0 >= valid_lens[b])
// 512 threads: hq = t&63 (h0=hq*4), rg = t>>6 (rows 2rg, 2rg+1).
// W loads are float4 over h (contiguous 1KB per wave per d).
// ---------------------------------------------------------------------------
__global__ __launch_bounds__(512) void proj_kernel(
    const float* __restrict__ queries, const float* __restrict__ keys,
    const float* __restrict__ Wq, const float* __restrict__ Wk,
    const int* __restrict__ valid_lens,
    float* __restrict__ qp, float* __restrict__ kpT)
{
    __shared__ __align__(16) float4 xs4[16 * 64];   // 16 rows x 256 d
    __shared__ __align__(16) float tile[16 * 260];  // transpose staging (k path)

    const int t = threadIdx.x;
    const bool isQ = (blockIdx.x < 64);
    const float* X; const float* W; int b, r0;
    if (isQ) {
        b = blockIdx.x >> 3; r0 = (blockIdx.x & 7) * 16;
        X = queries + ((size_t)b * TQ_ + r0) * D_;  W = Wq;
    } else {
        int id = blockIdx.x - 64;
        b = id >> 5; r0 = (id & 31) * 16;
        if (r0 >= valid_lens[b]) return;   // masked keys never read downstream
        X = keys + ((size_t)b * TK_ + r0) * D_;     W = Wk;
    }

    // stage 16 x 256 input tile as float4 (coalesced)
    const float4* X4 = reinterpret_cast<const float4*>(X);
    xs4[t]       = X4[t];
    xs4[t + 512] = X4[t + 512];
    __syncthreads();

    const int hq = t & 63;          // h0 = hq*4
    const int rg = t >> 6;          // 0..7
    const int rA = rg * 2, rB = rA + 1;
    const float4* W4 = reinterpret_cast<const float4*>(W) + hq;

    float4 a0 = make_float4(0.f, 0.f, 0.f, 0.f);
    float4 a1 = make_float4(0.f, 0.f, 0.f, 0.f);

#pragma unroll 4
    for (int d4 = 0; d4 < 64; ++d4) {
        const float4 xa = xs4[rA * 64 + d4];
        const float4 xb = xs4[rB * 64 + d4];
        const float4 w0 = W4[(size_t)(d4 * 4 + 0) * 64];
        const float4 w1 = W4[(size_t)(d4 * 4 + 1) * 64];
        const float4 w2 = W4[(size_t)(d4 * 4 + 2) * 64];
        const float4 w3 = W4[(size_t)(d4 * 4 + 3) * 64];
        a0.x = fmaf(w0.x, xa.x, a0.x); a0.y = fmaf(w0.y, xa.x, a0.y);
        a0.z = fmaf(w0.z, xa.x, a0.z); a0.w = fmaf(w0.w, xa.x, a0.w);
        a1.x = fmaf(w0.x, xb.x, a1.x); a1.y = fmaf(w0.y, xb.x, a1.y);
        a1.z = fmaf(w0.z, xb.x, a1.z); a1.w = fmaf(w0.w, xb.x, a1.w);
        a0.x = fmaf(w1.x, xa.y, a0.x); a0.y = fmaf(w1.y, xa.y, a0.y);
        a0.z = fmaf(w1.z, xa.y, a0.z); a0.w = fmaf(w1.w, xa.y, a0.w);
        a1.x = fmaf(w1.x, xb.y, a1.x); a1.y = fmaf(w1.y, xb.y, a1.y);
        a1.z = fmaf(w1.z, xb.y, a1.z); a1.w = fmaf(w1.w, xb.y, a1.w);
        a0.x = fmaf(w2.x, xa.z, a0.x); a0.y = fmaf(w2.y, xa.z, a0.y);
        a0.z = fmaf(w2.z, xa.z, a0.z); a0.w = fmaf(w2.w, xa.z, a0.w);
        a1.x = fmaf(w2.x, xb.z, a1.x); a1.y = fmaf(w2.y, xb.z, a1.y);
        a1.z = fmaf(w2.z, xb.z, a1.z); a1.w = fmaf(w2.w, xb.z, a1.w);
        a0.x = fmaf(w3.x, xa.w, a0.x); a0.y = fmaf(w3.y, xa.w, a0.y);
        a0.z = fmaf(w3.z, xa.w, a0.z); a0.w = fmaf(w3.w, xa.w, a0.w);
        a1.x = fmaf(w3.x, xb.w, a1.x); a1.y = fmaf(w3.y, xb.w, a1.y);
        a1.z = fmaf(w3.z, xb.w, a1.z); a1.w = fmaf(w3.w, xb.w, a1.w);
    }
    a0.x *= KSCALE; a0.y *= KSCALE; a0.z *= KSCALE; a0.w *= KSCALE;
    a1.x *= KSCALE; a1.y *= KSCALE; a1.z *= KSCALE; a1.w *= KSCALE;

    if (isQ) {
        float* dst = qp + ((size_t)b * TQ_ + r0) * H_ + hq * 4;
        *reinterpret_cast<float4*>(dst + (size_t)rA * H_) = a0;
        *reinterpret_cast<float4*>(dst + (size_t)rB * H_) = a1;
    } else {
        // transpose through LDS: tile[r][h], then write kpT[h][k] in 32B chunks
        *reinterpret_cast<float4*>(&tile[rA * 260 + hq * 4]) = a0;
        *reinterpret_cast<float4*>(&tile[rB * 260 + hq * 4]) = a1;
        __syncthreads();
        const int h = t >> 1, half = t & 1;
        float v[8];
#pragma unroll
        for (int i = 0; i < 8; ++i) v[i] = tile[(half * 8 + i) * 260 + h];
        float* dst = kpT + (size_t)b * (H_ * TK_) + (size_t)h * TK_ + r0 + half * 8;
        *reinterpret_cast<float4*>(dst)     = make_float4(v[0], v[1], v[2], v[3]);
        *reinterpret_cast<float4*>(dst + 4) = make_float4(v[4], v[5], v[6], v[7]);
    }
}

// ---------------------------------------------------------------------------
// Kernel 2: fused scores + masked softmax + PV. TWO q-rows per block.
// grid (64 qpair, 8 b) = 512 blocks, 512 threads (2 blocks/CU; stride-256
// co-resident blocks get b and b+4 -> len-work balances).
// Score: thread owns 4 consecutive k (float4 kpT load = 1KB/wave contiguous)
// x 2 q x h-quarter (hg = t>>7, 64 h each). Odd waves (k>=256) skip when
// len <= 256. Partials reduced via LDS, then min-softmax + PV as before.
// ---------------------------------------------------------------------------
__global__ __launch_bounds__(512) void attn_kernel(
    const float* __restrict__ qp, const float* __restrict__ kpT,
    const float* __restrict__ values, const int* __restrict__ valid_lens,
    const float* __restrict__ wv, float* __restrict__ out)
{
    __shared__ __align__(16) float2 qw2[H_];    // (q0', q1') pre-scaled
    __shared__ __align__(16) float wvs[H_];
    __shared__ __align__(16) float paccA[4 * TK_];  // [hg][k] partial acc q0
    __shared__ __align__(16) float paccB[4 * TK_];  // [hg][k] partial acc q1
    __shared__ __align__(16) float2 pe2[TK_];   // unnormalized probs (q0,q1)
    __shared__ float redm[2][8], reds[2][8];
    __shared__ float acch[2][256];              // PV half-1 partials

    const int t = threadIdx.x;
    const int b = blockIdx.y;
    const int q0 = blockIdx.x * 2;
    const int len = valid_lens[b];

    // stage q-pair + wv
    const float* qpb = qp + ((size_t)b * TQ_ + q0) * H_;
    if (t < 256) qw2[t] = make_float2(qpb[t], qpb[H_ + t]);
    else         wvs[t - 256] = wv[t - 256];
    __syncthreads();

    // ---- score: kq = t&127 (k0 = 4*kq), hg = t>>7 (h in [hg*64, hg*64+64)) ----
    const int kq = t & 127;
    const int hg = t >> 7;
    const int wid = t >> 6, lane = t & 63;
    float4 A0 = make_float4(0.f, 0.f, 0.f, 0.f);
    float4 A1 = make_float4(0.f, 0.f, 0.f, 0.f);

    if ((wid & 1) * 256 < len) {               // wave-uniform skip (k-half)
        const float* kbase = kpT + (size_t)b * (H_ * TK_) + (size_t)(hg * 64) * TK_ + kq * 4;
#pragma unroll 4
        for (int i = 0; i < 64; ++i) {
            const float4 kk = *reinterpret_cast<const float4*>(kbase + (size_t)i * TK_);
            const int h = hg * 64 + i;
            const float2 q2 = qw2[h];
            const float w = wvs[h];
            A0.x = fmaf(w, fast_rcp(1.0f + fast_exp2(q2.x + kk.x)), A0.x);
            A0.y = fmaf(w, fast_rcp(1.0f + fast_exp2(q2.x + kk.y)), A0.y);
            A0.z = fmaf(w, fast_rcp(1.0f + fast_exp2(q2.x + kk.z)), A0.z);
            A0.w = fmaf(w, fast_rcp(1.0f + fast_exp2(q2.x + kk.w)), A0.w);
            A1.x = fmaf(w, fast_rcp(1.0f + fast_exp2(q2.y + kk.x)), A1.x);
            A1.y = fmaf(w, fast_rcp(1.0f + fast_exp2(q2.y + kk.y)), A1.y);
            A1.z = fmaf(w, fast_rcp(1.0f + fast_exp2(q2.y + kk.z)), A1.z);
            A1.w = fmaf(w, fast_rcp(1.0f + fast_exp2(q2.y + kk.w)), A1.w);
        }
    }
    *reinterpret_cast<float4*>(&paccA[hg * TK_ + kq * 4]) = A0;
    *reinterpret_cast<float4*>(&paccB[hg * TK_ + kq * 4]) = A1;
    __syncthreads();

    // ---- combine h-quarters; masked softmax over k (min-acc == max-score) ----
    const int k = t;
    float a0 = ((paccA[k] + paccA[TK_ + k]) + (paccA[2 * TK_ + k] + paccA[3 * TK_ + k]));
    float a1 = ((paccB[k] + paccB[TK_ + k]) + (paccB[2 * TK_ + k] + paccB[3 * TK_ + k]));

    const bool valid = (k < len);
    const float BIG = 3.0e38f;

    float m0 = wave_red_min(valid ? a0 : BIG);
    float m1 = wave_red_min(valid ? a1 : BIG);
    if (lane == 0) { redm[0][wid] = m0; redm[1][wid] = m1; }
    __syncthreads();
    float mr0 = redm[0][0], mr1 = redm[1][0];
#pragma unroll
    for (int i = 1; i < 8; ++i) { mr0 = fminf(mr0, redm[0][i]); mr1 = fminf(mr1, redm[1][i]); }

    const float e0 = valid ? fast_exp2((mr0 - a0) * KSCALE) : 0.f;
    const float e1 = valid ? fast_exp2((mr1 - a1) * KSCALE) : 0.f;
    pe2[k] = make_float2(e0, e1);
    float S0 = wave_red_sum(e0);
    float S1 = wave_red_sum(e1);
    if (lane == 0) { reds[0][wid] = S0; reds[1][wid] = S1; }
    __syncthreads();
    float s0 = 0.f, s1 = 0.f;
#pragma unroll
    for (int i = 0; i < 8; ++i) { s0 += reds[0][i]; s1 += reds[1][i]; }
    const float rs0 = 1.0f / s0, rs1 = 1.0f / s1;

    // ---- PV: 2-way split-k, dead 64-k chunks skipped ----
    const int d = t & 255;
    const int half = t >> 8;
    float c0 = 0.f, c1 = 0.f;
    const float* vb = values + (size_t)b * (TK_ * D_) + (size_t)(half * 256) * D_ + d;
    const float2* pb = &pe2[half * 256];
#pragma unroll
    for (int c = 0; c < 4; ++c) {
        if (half * 256 + c * 64 < len) {
#pragma unroll 8
            for (int i = 0; i < 64; ++i) {
                const int kk = c * 64 + i;
                const float v = vb[(size_t)kk * D_];
                const float2 p = pb[kk];
                c0 = fmaf(p.x, v, c0);
                c1 = fmaf(p.y, v, c1);
            }
        }
    }
    if (half == 1) { acch[0][d] = c0; acch[1][d] = c1; }
    __syncthreads();
    if (half == 0) {
        float* ob = out + ((size_t)b * TQ_ + q0) * D_ + d;
        ob[0]  = (c0 + acch[0][d]) * rs0;
        ob[D_] = (c1 + acch[1][d]) * rs1;
    }
}

extern "C" void kernel_launch(void* const* d_in, const int* in_sizes, int n_in,
                              void* d_out, int out_size, void* d_ws, size_t ws_size,
                              hipStream_t stream) {
    const float* queries    = (const float*)d_in[0];
    const float* keys       = (const float*)d_in[1];
    const float* values     = (const float*)d_in[2];
    const int*   valid_lens = (const int*)  d_in[3];
    const float* Wq         = (const float*)d_in[4];
    const float* Wk         = (const float*)d_in[5];
    const float* wv         = (const float*)d_in[6];
    float* out = (float*)d_out;

    float* qp  = (float*)d_ws;                       // B*Tq*H  = 262144 f32
    float* kpT = qp + (size_t)B_ * TQ_ * H_;         // B*H*Tk  = 1048576 f32

    proj_kernel<<<320, 512, 0, stream>>>(queries, keys, Wq, Wk, valid_lens, qp, kpT);
    attn_kernel<<<dim3(TQ_ / 2, B_), 512, 0, stream>>>(qp, kpT, values, valid_lens, wv, out);
}